// Round 8
// baseline (161.486 us; speedup 1.0000x reference)
//
#include <hip/hip_runtime.h>

typedef __bf16   bf16x8 __attribute__((ext_vector_type(8)));
typedef float    f32x4  __attribute__((ext_vector_type(4)));
typedef float    f32x2  __attribute__((ext_vector_type(2)));
typedef uint32_t u32x4  __attribute__((ext_vector_type(4)));

constexpr int N_ = 16384;
constexpr int D_ = 16;
constexpr int P_ = 8;
constexpr int H_ = 128;
constexpr int M_ = 50;

// pack two f32 -> one bf16x2 register word (round-half-up; 3 VALU ops)
__device__ __forceinline__ uint32_t pk_bf16(float a, float b) {
    uint32_t ua = __builtin_bit_cast(uint32_t, a) + 0x8000u;
    uint32_t ub = __builtin_bit_cast(uint32_t, b) + 0x8000u;
    return __builtin_amdgcn_perm(ub, ua, 0x07060302u);   // [a.hi16 | b.hi16]
}
__device__ __forceinline__ uint32_t pk_relu_bf16(float a, float b) {
    return pk_bf16(fmaxf(a, 0.0f), fmaxf(b, 0.0f));
}
__device__ __forceinline__ u32x4 pk_frag(f32x4 a, f32x4 b) {
    u32x4 u;
    u[0] = pk_relu_bf16(a[0], a[1]);
    u[1] = pk_relu_bf16(a[2], a[3]);
    u[2] = pk_relu_bf16(b[0], b[1]);
    u[3] = pk_relu_bf16(b[2], b[3]);
    return u;
}

// R8: PARITY time-split, 2 waves/SIMD. Z never feeds back into X, so both
// waves roll X every step (4 fma, bit-identical) while wave 0 evaluates the
// MLP only at even steps and wave 1 only at odd steps. No barriers in the
// loop; two independent 44-MFMA streams per SIMD hide each other's latency.
// Register diet vs R7 (which spilled at 12 MB scratch writes): W2 streamed
// from a 32KB LDS table (one-time fill), L1/L2 done in ct-halves so only 16
// accumulator regs are live at once. Wave 1's noise loads hit L1 (same lines
// as wave 0) -> no extra HBM traffic.
__global__ __launch_bounds__(128, 2)
void sde_fused(const float* __restrict__ X0,
               const float* __restrict__ V0,
               const float* __restrict__ Yobs,
               const float* __restrict__ noise,
               const float* __restrict__ W1, const float* __restrict__ b1,
               const float* __restrict__ W2, const float* __restrict__ b2,
               const float* __restrict__ W3, const float* __restrict__ b3,
               float* __restrict__ out)
{
    __shared__ u32x4 w2lds[32][64];   // 32 KB: [ct*4+kt][lane]
    __shared__ float vsh[16];

    const int tid  = threadIdx.x;
    const int wv   = tid >> 6;      // parity: wave 0 = even steps, wave 1 = odd
    const int lane = tid & 63;
    const int n    = lane & 15;
    const int q    = lane >> 4;
    const int gr   = blockIdx.x * 16 + n;

    const float dt   = 0.02f;
    const float sqdt = 0.1414213562373095f;

    // ---- W2 -> LDS (each wave fills 16 of 32 fragments) ----
#pragma unroll
    for (int i = 0; i < 16; ++i) {
        int idx = wv * 16 + i;
        int ct = idx >> 2, kt = idx & 3;
        u32x4 u;
#pragma unroll
        for (int w = 0; w < 4; ++w) {
            int h0 = (kt * 2 + (w >> 1)) * 16 + q * 4 + (w & 1) * 2;
            u[w] = pk_bf16(W2[h0 * H_ + ct * 16 + n],
                           W2[(h0 + 1) * H_ + ct * 16 + n]);
        }
        w2lds[idx][lane] = u;
    }

    // ---- register weights: W1, W3, biases ----
    bf16x8 w1f[8];
#pragma unroll
    for (int ct = 0; ct < 8; ++ct) {
        u32x4 u;
        u[0] = pk_bf16(W1[(1 + q * 4 + 0) * H_ + ct * 16 + n],
                       W1[(1 + q * 4 + 1) * H_ + ct * 16 + n]);
        u[1] = pk_bf16(W1[(1 + q * 4 + 2) * H_ + ct * 16 + n],
                       W1[(1 + q * 4 + 3) * H_ + ct * 16 + n]);
        u[2] = pk_bf16(W1[(17 + q * 2 + 0) * H_ + ct * 16 + n],
                       W1[(17 + q * 2 + 1) * H_ + ct * 16 + n]);
        u[3] = (q == 0) ? pk_bf16(b1[ct * 16 + n], W1[ct * 16 + n]) : 0u;
        w1f[ct] = __builtin_bit_cast(bf16x8, u);
    }
    bf16x8 w3f[4];
#pragma unroll
    for (int kt = 0; kt < 4; ++kt) {
        u32x4 u;
#pragma unroll
        for (int w = 0; w < 4; ++w) {
            int h0 = (kt * 2 + (w >> 1)) * 16 + q * 4 + (w & 1) * 2;
            u[w] = pk_bf16(W3[h0 * D_ + n], W3[(h0 + 1) * D_ + n]);
        }
        w3f[kt] = __builtin_bit_cast(bf16x8, u);
    }
    f32x4 b2r[8];
#pragma unroll
    for (int ct = 0; ct < 8; ++ct)
#pragma unroll
        for (int r = 0; r < 4; ++r) b2r[ct][r] = b2[ct * 16 + q * 4 + r];
    f32x4 b3r;
#pragma unroll
    for (int r = 0; r < 4; ++r) b3r[r] = b3[q * 4 + r];

    // ---- state ----
    f32x4 x = *(const f32x4*)&X0[gr * D_ + q * 4];
    f32x2 y2 = *(const f32x2*)&Yobs[gr * P_ + q * 2];
    const uint32_t yw = pk_bf16(y2[0], y2[1]);

    const float* npb = noise + (size_t)gr * D_ + q * 4;
    const size_t stp = (size_t)N_ * D_;
    f32x4 e0 = *(const f32x4*)(npb);            // step 2i
    f32x4 e1 = *(const f32x4*)(npb + stp);      // step 2i+1
    float tw = wv ? dt : 0.0f;                  // this wave's MLP time
    float vacc = 0.0f;

    __syncthreads();   // w2lds ready

#pragma unroll 1
    for (int i = 0; i < 25; ++i) {
        // prefetch next pair (clamped at tail; unused extra loads are cheap)
        int sa = 2 * i + 2; if (sa > 48) sa = 48;
        f32x4 pa = *(const f32x4*)(npb + (size_t)sa * stp);
        f32x4 pb = *(const f32x4*)(npb + (size_t)(sa + 1) * stp);

        // ---- roll X; pick this wave's MLP input & Brownian increment ----
        f32x4 x1, xin, wnv;
#pragma unroll
        for (int r = 0; r < 4; ++r) x1[r] = fmaf(x[r], 0.98f, sqdt * e0[r]);
#pragma unroll
        for (int r = 0; r < 4; ++r) {
            xin[r] = wv ? x1[r] : x[r];
            wnv[r] = sqdt * (wv ? e1[r] : e0[r]);
            x[r]   = fmaf(x1[r], 0.98f, sqdt * e1[r]);   // X_{2i+2}
        }

        // ---- layer-1 input fragment ----
        u32x4 au;
        au[0] = pk_bf16(xin[0], xin[1]);
        au[1] = pk_bf16(xin[2], xin[3]);
        au[2] = yw;
        au[3] = (q == 0) ? pk_bf16(1.0f, tw) : 0u;
        bf16x8 a0 = __builtin_bit_cast(bf16x8, au);

        // ---- layer 1 in ct-halves (<=16 acc regs live) ----
        f32x4 c0, c1, c2, c3;
        c0 = __builtin_amdgcn_mfma_f32_16x16x32_bf16(w1f[0], a0, (f32x4){0.f,0.f,0.f,0.f}, 0, 0, 0);
        c1 = __builtin_amdgcn_mfma_f32_16x16x32_bf16(w1f[1], a0, (f32x4){0.f,0.f,0.f,0.f}, 0, 0, 0);
        c2 = __builtin_amdgcn_mfma_f32_16x16x32_bf16(w1f[2], a0, (f32x4){0.f,0.f,0.f,0.f}, 0, 0, 0);
        c3 = __builtin_amdgcn_mfma_f32_16x16x32_bf16(w1f[3], a0, (f32x4){0.f,0.f,0.f,0.f}, 0, 0, 0);
        bf16x8 h1b0 = __builtin_bit_cast(bf16x8, pk_frag(c0, c1));
        bf16x8 h1b1 = __builtin_bit_cast(bf16x8, pk_frag(c2, c3));
        c0 = __builtin_amdgcn_mfma_f32_16x16x32_bf16(w1f[4], a0, (f32x4){0.f,0.f,0.f,0.f}, 0, 0, 0);
        c1 = __builtin_amdgcn_mfma_f32_16x16x32_bf16(w1f[5], a0, (f32x4){0.f,0.f,0.f,0.f}, 0, 0, 0);
        c2 = __builtin_amdgcn_mfma_f32_16x16x32_bf16(w1f[6], a0, (f32x4){0.f,0.f,0.f,0.f}, 0, 0, 0);
        c3 = __builtin_amdgcn_mfma_f32_16x16x32_bf16(w1f[7], a0, (f32x4){0.f,0.f,0.f,0.f}, 0, 0, 0);
        bf16x8 h1b2 = __builtin_bit_cast(bf16x8, pk_frag(c0, c1));
        bf16x8 h1b3 = __builtin_bit_cast(bf16x8, pk_frag(c2, c3));

        // ---- layer 2 in ct-halves, W2 fragments streamed from LDS ----
        f32x4 d0, d1, d2, d3;
#define L2CT(dst, ct)                                                                   \
        dst = b2r[ct];                                                                  \
        dst = __builtin_amdgcn_mfma_f32_16x16x32_bf16(                                  \
            __builtin_bit_cast(bf16x8, w2lds[(ct)*4+0][lane]), h1b0, dst, 0, 0, 0);     \
        dst = __builtin_amdgcn_mfma_f32_16x16x32_bf16(                                  \
            __builtin_bit_cast(bf16x8, w2lds[(ct)*4+1][lane]), h1b1, dst, 0, 0, 0);     \
        dst = __builtin_amdgcn_mfma_f32_16x16x32_bf16(                                  \
            __builtin_bit_cast(bf16x8, w2lds[(ct)*4+2][lane]), h1b2, dst, 0, 0, 0);     \
        dst = __builtin_amdgcn_mfma_f32_16x16x32_bf16(                                  \
            __builtin_bit_cast(bf16x8, w2lds[(ct)*4+3][lane]), h1b3, dst, 0, 0, 0);
        L2CT(d0, 0) L2CT(d1, 1) L2CT(d2, 2) L2CT(d3, 3)
        bf16x8 h2b0 = __builtin_bit_cast(bf16x8, pk_frag(d0, d1));
        bf16x8 h2b1 = __builtin_bit_cast(bf16x8, pk_frag(d2, d3));
        L2CT(d0, 4) L2CT(d1, 5) L2CT(d2, 6) L2CT(d3, 7)
        bf16x8 h2b2 = __builtin_bit_cast(bf16x8, pk_frag(d0, d1));
        bf16x8 h2b3 = __builtin_bit_cast(bf16x8, pk_frag(d2, d3));
#undef L2CT

        // ---- layer 3 ----
        f32x4 za = __builtin_amdgcn_mfma_f32_16x16x32_bf16(w3f[0], h2b0, b3r, 0, 0, 0);
        za = __builtin_amdgcn_mfma_f32_16x16x32_bf16(w3f[1], h2b1, za, 0, 0, 0);
        f32x4 zb = __builtin_amdgcn_mfma_f32_16x16x32_bf16(
            w3f[2], h2b2, (f32x4){0.f,0.f,0.f,0.f}, 0, 0, 0);
        zb = __builtin_amdgcn_mfma_f32_16x16x32_bf16(w3f[3], h2b3, zb, 0, 0, 0);

        // ---- V partial for this wave's step ----
#pragma unroll
        for (int r = 0; r < 4; ++r) {
            float z = za[r] + zb[r];
            vacc = fmaf(z, wnv[r], fmaf(0.01f * z, z, vacc));
        }

        e0 = pa; e1 = pb;
        tw += 0.04f;
    }

    // ---- merge V partials (one barrier at the end) ----
    float part = vacc;
    part += __shfl_xor(part, 16);
    part += __shfl_xor(part, 32);
    if (wv == 1 && q == 0) vsh[n] = part;
    __syncthreads();

    if (wv == 0) {
        *(f32x4*)&out[gr * D_ + q * 4] = x;
        if (q == 0) out[N_ * D_ + gr] = V0[gr] + part + vsh[n];
    }
}

extern "C" void kernel_launch(void* const* d_in, const int* in_sizes, int n_in,
                              void* d_out, int out_size, void* d_ws, size_t ws_size,
                              hipStream_t stream)
{
    const float* X0 = (const float*)d_in[0];
    const float* V0 = (const float*)d_in[1];
    const float* Y  = (const float*)d_in[2];
    const float* nz = (const float*)d_in[3];
    const float* W1 = (const float*)d_in[4];
    const float* b1 = (const float*)d_in[5];
    const float* W2 = (const float*)d_in[6];
    const float* b2 = (const float*)d_in[7];
    const float* W3 = (const float*)d_in[8];
    const float* b3 = (const float*)d_in[9];
    float* out = (float*)d_out;

    sde_fused<<<N_ / 16, 128, 0, stream>>>(X0, V0, Y, nz, W1, b1, W2, b2, W3, b3, out);
}